// Round 4
// baseline (1094.744 us; speedup 1.0000x reference)
//
#include <hip/hip_runtime.h>

#define TNODES 65536
#define NGRAPH 16
#define NNODE  4096
#define INCH   256
#define HID    512

using u16 = unsigned short;
using u32 = unsigned int;
using v8s = __attribute__((ext_vector_type(8))) short;   // 8 bf16 (4 VGPRs)
using v4f = __attribute__((ext_vector_type(4))) float;   // 4 fp32 acc

__device__ __forceinline__ float bf2f(u16 u) {
    union { u32 i; float f; } v; v.i = ((u32)u) << 16; return v.f;
}
__device__ __forceinline__ u16 f2bf(float f) {
    union { float f; u32 i; } v; v.f = f;
    u32 x = v.i;
    return (u16)((x + 0x7fffu + ((x >> 16) & 1u)) >> 16);
}
__device__ __forceinline__ void up4(uint2 p, float* f) {
    f[0] = __uint_as_float(p.x << 16); f[1] = __uint_as_float(p.x & 0xffff0000u);
    f[2] = __uint_as_float(p.y << 16); f[3] = __uint_as_float(p.y & 0xffff0000u);
}
__device__ __forceinline__ uint2 pk4(float a, float b, float c, float d) {
    uint2 r;
    r.x = (u32)f2bf(a) | ((u32)f2bf(b) << 16);
    r.y = (u32)f2bf(c) | ((u32)f2bf(d) << 16);
    return r;
}

#define MFMA(a, b, c) __builtin_amdgcn_mfma_f32_16x16x32_bf16((a), (b), (c), 0, 0, 0)

// async global->LDS, 16B per lane. dest = wave-uniform base + lane*16 (linear).
#define GLD16(gp, sp) __builtin_amdgcn_global_load_lds( \
    (const __attribute__((address_space(1))) u32*)(const void*)(gp), \
    (__attribute__((address_space(3))) u32*)(void*)(sp), 16, 0, 0)

// compile-time memory fence (keeps loads/stores from crossing raw barriers)
#define CFENCE() asm volatile("" ::: "memory")

// ---------------- fp32 -> bf16 convert, vectorized ----------------
__global__ void k_cvt4(const float* __restrict__ s, u16* __restrict__ d, int n4) {
    for (int i = blockIdx.x * blockDim.x + threadIdx.x; i < n4; i += gridDim.x * blockDim.x) {
        float4 f = ((const float4*)s)[i];
        ((uint2*)d)[i] = pk4(f.x, f.y, f.z, f.w);
    }
}

__global__ void k_zero(float* __restrict__ p, int n) {
    int i = blockIdx.x * 256 + threadIdx.x;
    if (i < n) p[i] = 0.f;
}

// ---------------- sum 4 bf16 partial planes -> bf16 ----------------
__global__ void k_red4(const u16* __restrict__ p, u16* __restrict__ o, int n8) {
    const size_t P = (size_t)NGRAPH * HID * HID;
    for (int i = blockIdx.x * blockDim.x + threadIdx.x; i < n8; i += gridDim.x * blockDim.x) {
        size_t b = (size_t)i * 8;
        float s[8] = {0.f, 0.f, 0.f, 0.f, 0.f, 0.f, 0.f, 0.f};
        #pragma unroll
        for (int ss = 0; ss < 4; ++ss) {
            v8s v = *(const v8s*)(p + ss * P + b);
            const u16* vp = (const u16*)&v;
            #pragma unroll
            for (int j = 0; j < 8; ++j) s[j] += bf2f(vp[j]);
        }
        uint2 lo = pk4(s[0], s[1], s[2], s[3]);
        uint2 hi = pk4(s[4], s[5], s[6], s[7]);
        uint4 w; w.x = lo.x; w.y = lo.y; w.z = hi.x; w.w = hi.y;
        *(uint4*)(o + b) = w;
    }
}

// =====================================================================
// Shared GEMM core: C[64 x 512] = Act[64 rows, stride LDK] @ W[512 rows]^T
// over a KLEN-long reduction chunk. 512 threads = 8 waves (2 row-groups x
// 4 col-groups). BK=32, double-buffered LDS via global_load_lds(16B).
// XOR-swizzle (slot ^= (row>>1)&3) applied on the GLOBAL source (rule #21)
// + same XOR on ds_read.
// T4 counted-vmcnt schedule: raw s_barriers; prefetch for tile k+2 issued
// after the consume-barrier; per-step wait is vmcnt(L) (L = own in-flight
// next-tile loads: 5 for waves 0-3 which also stage A, 4 for waves 4-7),
// vmcnt(0) only on the last step. Loads get a full K-step of slack and the
// queue is never drained mid-loop.
// =====================================================================
template<int LDK, int KLEN>
__device__ __forceinline__ void gemm_core(const u16* __restrict__ A,
                                          const u16* __restrict__ W,
                                          u16* sA, u16* sW, v4f (&acc)[8][2]) {
    const int t = threadIdx.x, lane = t & 63;
    const int q = lane >> 4, m15 = lane & 15;
    const int w = t >> 6, wr = w >> 2, wc = w & 3;

    #pragma unroll
    for (int n = 0; n < 8; ++n)
        #pragma unroll
        for (int rt = 0; rt < 2; ++rt)
            #pragma unroll
            for (int e = 0; e < 4; ++e) acc[n][rt][e] = 0.f;

    int aoff[2], woff[8];
    #pragma unroll
    for (int rt = 0; rt < 2; ++rt) {
        int r = wr * 32 + rt * 16 + m15;
        aoff[rt] = r * 32 + ((q ^ ((r >> 1) & 3)) * 8);
    }
    #pragma unroll
    for (int n = 0; n < 8; ++n) {
        int r = wc * 128 + n * 16 + m15;
        woff[n] = r * 32 + ((q ^ ((r >> 1) & 3)) * 8);
    }

    auto stage = [&](int k0, int buf) {
        u16* dW = sW + buf * (512 * 32);
        #pragma unroll
        for (int p = 0; p < 4; ++p) {
            int sf = p * 512 + t, row = sf >> 2, sl = sf & 3;
            int gc = k0 + ((sl ^ ((row >> 1) & 3)) * 8);
            GLD16(W + (size_t)row * LDK + gc, dW + sf * 8);
        }
        if (t < 256) {
            int row = t >> 2, sl = t & 3;
            int gc = k0 + ((sl ^ ((row >> 1) & 3)) * 8);
            GLD16(A + (size_t)row * LDK + gc, sA + buf * (64 * 32) + t * 8);
        }
    };

    const int KT = KLEN / 32;
    stage(0, 0);
    stage(32, 1);
    int cur = 0;
    const bool lowt = (t < 256);          // wave-uniform (waves 0-3)
    for (int kt = 0; kt < KT; ++kt) {
        // wait for MY stage(kt) loads; allow stage(kt+1)'s to stay in flight
        if (kt + 1 < KT) {
            if (lowt) asm volatile("s_waitcnt vmcnt(5)" ::: "memory");
            else      asm volatile("s_waitcnt vmcnt(4)" ::: "memory");
        } else {
            asm volatile("s_waitcnt vmcnt(0)" ::: "memory");
        }
        __builtin_amdgcn_s_barrier();     // all threads' stage(kt) data visible
        CFENCE();
        __builtin_amdgcn_sched_barrier(0);
        const u16* cA = sA + cur * (64 * 32);
        const u16* cW = sW + cur * (512 * 32);
        v8s b0 = *(const v8s*)(cA + aoff[0]);
        v8s b1 = *(const v8s*)(cA + aoff[1]);
        #pragma unroll
        for (int n = 0; n < 8; ++n) {
            v8s af = *(const v8s*)(cW + woff[n]);
            acc[n][0] = MFMA(af, b0, acc[n][0]);
            acc[n][1] = MFMA(af, b1, acc[n][1]);
        }
        CFENCE();
        __builtin_amdgcn_s_barrier();     // everyone done reading buf[cur]
        CFENCE();
        if (kt + 2 < KT) stage((kt + 2) * 32, cur);   // overwrite consumed buf
        cur ^= 1;
    }
}

// acc element (n,rt,e) <-> A-row wr*32 + rt*16 + (lane&15),
//                          W-row wc*128 + n*16 + (lane>>4)*4 + e.

// transpose swizzle: X(c) = (((c>>2)&3)<<4) ^ ((c&3)<<3)  [multiple of 8, <64]
// write side: per store instruction the 4 q-groups get disjoint 8-bank
// quarters -> conflict-free (2 rows/bank = free). read side: 8 distinct
// 16B-slot phases per 8 channels.
__device__ __forceinline__ int tswz(int c) {
    return (((c >> 2) & 3) << 4) ^ ((c & 3) << 3);
}

// ---------------- fc0 + LN + ReLU ----------------
__launch_bounds__(512, 4)
__global__ void k_fc(const u16* __restrict__ xb, const u16* __restrict__ wb,
                     const float* __restrict__ bias, const float* __restrict__ lg,
                     const float* __restrict__ lb, u16* __restrict__ h) {
    __shared__ u16 sA[2][64 * 32];
    __shared__ u16 sW[2][512 * 32];
    __shared__ float red[2][64][4];
    __shared__ float rowv[2][64];
    const int t = threadIdx.x, lane = t & 63, w = t >> 6;
    const int q = lane >> 4, m15 = lane & 15;
    const int wr = w >> 2, wc = w & 3;
    const int bx = (int)blockIdx.x;
    const int swz = (bx & 7) * ((int)gridDim.x >> 3) + (bx >> 3);
    const int r0 = swz * 64;
    v4f acc[8][2];
    gemm_core<INCH, INCH>(xb + (size_t)r0 * INCH, wb, &sA[0][0], &sW[0][0], acc);

    float sm0 = 0.f, sm1 = 0.f, sq0 = 0.f, sq1 = 0.f;
    #pragma unroll
    for (int n = 0; n < 8; ++n) {
        int c = wc * 128 + n * 16 + q * 4;
        float4 bi = *(const float4*)(bias + c);
        const float* bp = &bi.x;
        #pragma unroll
        for (int rt = 0; rt < 2; ++rt)
            #pragma unroll
            for (int e = 0; e < 4; ++e) {
                float a = acc[n][rt][e] + bp[e];
                acc[n][rt][e] = a;
                if (rt == 0) { sm0 += a; sq0 += a * a; } else { sm1 += a; sq1 += a * a; }
            }
    }
    sm0 += __shfl_xor(sm0, 16); sm0 += __shfl_xor(sm0, 32);
    sq0 += __shfl_xor(sq0, 16); sq0 += __shfl_xor(sq0, 32);
    sm1 += __shfl_xor(sm1, 16); sm1 += __shfl_xor(sm1, 32);
    sq1 += __shfl_xor(sq1, 16); sq1 += __shfl_xor(sq1, 32);
    if (lane < 16) {
        red[0][wr * 32 + m15][wc] = sm0; red[0][wr * 32 + 16 + m15][wc] = sm1;
        red[1][wr * 32 + m15][wc] = sq0; red[1][wr * 32 + 16 + m15][wc] = sq1;
    }
    __syncthreads();
    if (t < 64) {
        float tt = red[0][t][0] + red[0][t][1] + red[0][t][2] + red[0][t][3];
        float t2 = red[1][t][0] + red[1][t][1] + red[1][t][2] + red[1][t][3];
        float mu = tt * (1.f / HID);
        float rs = rsqrtf(t2 * (1.f / HID) - mu * mu + 1e-5f);
        rowv[0][t] = mu; rowv[1][t] = rs;
    }
    __syncthreads();
    #pragma unroll
    for (int n = 0; n < 8; ++n) {
        int c = wc * 128 + n * 16 + q * 4;
        float4 g4 = *(const float4*)(lg + c);
        float4 b4 = *(const float4*)(lb + c);
        #pragma unroll
        for (int rt = 0; rt < 2; ++rt) {
            int row = wr * 32 + rt * 16 + m15;
            float mu = rowv[0][row], rs = rowv[1][row];
            float v0 = (acc[n][rt][0] - mu) * rs * g4.x + b4.x;
            float v1 = (acc[n][rt][1] - mu) * rs * g4.y + b4.y;
            float v2 = (acc[n][rt][2] - mu) * rs * g4.z + b4.z;
            float v3 = (acc[n][rt][3] - mu) * rs * g4.w + b4.w;
            v0 = v0 > 0.f ? v0 : 0.f; v1 = v1 > 0.f ? v1 : 0.f;
            v2 = v2 > 0.f ? v2 : 0.f; v3 = v3 > 0.f ? v3 : 0.f;
            *(uint2*)&h[(size_t)(r0 + row) * HID + c] = pk4(v0, v1, v2, v3);
        }
    }
}

// ---------------- k/v projection + transposed outputs ----------------
// y==0: k -> eps + L2 row-normalize -> Kt[g][m][l] bf16, fused ks partial sums.
// y==1: v -> V fp32 identity (for attn2 epilogue) + Vt[g][d][l] bf16 (for kvmm).
// Transpose via swizzled LDS reuse of the GEMM sW buffer (64 KB = 512x64 u16).
__launch_bounds__(512, 4)
__global__ void k_proj(const u16* __restrict__ hsrc, const u16* __restrict__ wkb,
                       const u16* __restrict__ wvb, u16* __restrict__ kt,
                       u16* __restrict__ vt, float* __restrict__ vo,
                       float* __restrict__ ksum) {
    __shared__ char smem[8192 + 65536 + 1024 + 256];
    u16* sA = (u16*)smem;
    u16* sW = (u16*)(smem + 8192);
    u16* sT = sW;                                            // reuse after GEMM
    float (*red)[4] = (float(*)[4])(smem + 8192 + 65536);    // [64][4]
    float* rowv = (float*)(smem + 8192 + 65536 + 1024);      // [64]
    const int t = threadIdx.x, lane = t & 63, w = t >> 6;
    const int q = lane >> 4, m15 = lane & 15;
    const int wr = w >> 2, wc = w & 3;
    const int bx = (int)blockIdx.x;
    const int swz = (bx & 7) * ((int)gridDim.x >> 3) + (bx >> 3);
    const int r0 = swz * 64;
    const int g = swz >> 6;                  // 64 blocks per graph
    const int lbase = (swz & 63) * 64;
    const int mode = blockIdx.y;
    v4f acc[8][2];
    gemm_core<HID, HID>(hsrc + (size_t)r0 * HID, mode ? wvb : wkb,
                        sA, sW, acc);

    if (mode == 0) {
        float sq0 = 0.f, sq1 = 0.f;
        #pragma unroll
        for (int n = 0; n < 8; ++n)
            #pragma unroll
            for (int rt = 0; rt < 2; ++rt)
                #pragma unroll
                for (int e = 0; e < 4; ++e) {
                    float vv = acc[n][rt][e];
                    if (vv == 0.f) vv = 1e-6f;
                    acc[n][rt][e] = vv;
                    if (rt == 0) sq0 += vv * vv; else sq1 += vv * vv;
                }
        sq0 += __shfl_xor(sq0, 16); sq0 += __shfl_xor(sq0, 32);
        sq1 += __shfl_xor(sq1, 16); sq1 += __shfl_xor(sq1, 32);
        if (lane < 16) {
            red[wr * 32 + m15][wc] = sq0; red[wr * 32 + 16 + m15][wc] = sq1;
        }
        __syncthreads();
        if (t < 64)
            rowv[t] = rsqrtf(red[t][0] + red[t][1] + red[t][2] + red[t][3]);
        __syncthreads();
        #pragma unroll
        for (int n = 0; n < 8; ++n)
            #pragma unroll
            for (int rt = 0; rt < 2; ++rt) {
                int row = wr * 32 + rt * 16 + m15;
                float rn = rowv[row];
                #pragma unroll
                for (int e = 0; e < 4; ++e) {
                    int c = wc * 128 + n * 16 + q * 4 + e;
                    sT[(c << 6) + (row ^ tswz(c))] = f2bf(acc[n][rt][e] * rn);
                }
            }
        __syncthreads();
        const int ch = t;
        const int xs = (((ch >> 2) & 3) << 1) ^ (ch & 3);   // tswz(ch)>>3
        u16* op = kt + ((size_t)(g * 512 + ch)) * NNODE + lbase;
        float sum = 0.f;
        #pragma unroll
        for (int jj = 0; jj < 8; ++jj) {
            v8s cvec = *(const v8s*)&sT[(ch << 6) + jj * 8];
            int l0 = (jj ^ xs) * 8;
            *(v8s*)(op + l0) = cvec;
            const u16* cp = (const u16*)&cvec;
            #pragma unroll
            for (int i = 0; i < 8; ++i) sum += bf2f(cp[i]);
        }
        atomicAdd(&ksum[g * 512 + ch], sum);
    } else {
        #pragma unroll
        for (int n = 0; n < 8; ++n) {
            int c = wc * 128 + n * 16 + q * 4;
            #pragma unroll
            for (int rt = 0; rt < 2; ++rt) {
                int row = wr * 32 + rt * 16 + m15;
                float4 o = {acc[n][rt][0], acc[n][rt][1], acc[n][rt][2], acc[n][rt][3]};
                *(float4*)&vo[(size_t)(r0 + row) * HID + c] = o;
                #pragma unroll
                for (int e = 0; e < 4; ++e)
                    sT[((c + e) << 6) + (row ^ tswz(c + e))] = f2bf(acc[n][rt][e]);
            }
        }
        __syncthreads();
        const int ch = t;
        const int xs = (((ch >> 2) & 3) << 1) ^ (ch & 3);
        u16* op = vt + ((size_t)(g * 512 + ch)) * NNODE + lbase;
        #pragma unroll
        for (int jj = 0; jj < 8; ++jj) {
            v8s cvec = *(const v8s*)&sT[(ch << 6) + jj * 8];
            int l0 = (jj ^ xs) * 8;
            *(v8s*)(op + l0) = cvec;
        }
    }
}

// ---------------- kvsT partial[s][d][m] = sum_{l in split s} Vt[d][l]*Kt[m][l]
// grid: 512 blocks = 8 d-blocks x 4 l-splits x 16 graphs, chunked XCD swizzle.
// Plain bf16 stores (NO atomics); k_red4 sums the 4 planes afterwards.
__launch_bounds__(512, 4)
__global__ void k_kvmm2(const u16* __restrict__ kt, const u16* __restrict__ vt,
                        u16* __restrict__ kvp) {
    __shared__ u16 sA[2][64 * 32];
    __shared__ u16 sW[2][512 * 32];
    const int t = threadIdx.x, lane = t & 63, w = t >> 6;
    const int q = lane >> 4, m15 = lane & 15;
    const int wr = w >> 2, wc = w & 3;
    const int bx = (int)blockIdx.x;
    const int swz = (bx & 7) * 64 + (bx >> 3);   // 512 blocks, 64/XCD chunk
    const int db = swz & 7, s = (swz >> 3) & 3, g = swz >> 5;
    const u16* A = vt + ((size_t)(g * 512 + db * 64)) * NNODE + s * 1024;
    const u16* W = kt + ((size_t)(g * 512)) * NNODE + s * 1024;
    v4f acc[8][2];
    gemm_core<NNODE, 1024>(A, W, &sA[0][0], &sW[0][0], acc);
    u16* plane = kvp + (size_t)s * NGRAPH * HID * HID;
    #pragma unroll
    for (int n = 0; n < 8; ++n) {
        int m = wc * 128 + n * 16 + q * 4;
        #pragma unroll
        for (int rt = 0; rt < 2; ++rt) {
            int d = db * 64 + wr * 32 + rt * 16 + m15;
            *(uint2*)&plane[((size_t)(g * 512) + d) * 512 + m] =
                pk4(acc[n][rt][0], acc[n][rt][1], acc[n][rt][2], acc[n][rt][3]);
        }
    }
}

// ---------------- q projection + normalize + denom ----------------
__launch_bounds__(512, 4)
__global__ void k_qnorm(const u16* __restrict__ hsrc, const u16* __restrict__ qwb,
                        const float* __restrict__ ks, u16* __restrict__ qo,
                        float* __restrict__ dnv) {
    __shared__ u16 sA[2][64 * 32];
    __shared__ u16 sW[2][512 * 32];
    __shared__ float red[2][64][4];
    __shared__ float rowv[64];
    const int t = threadIdx.x, lane = t & 63, w = t >> 6;
    const int q = lane >> 4, m15 = lane & 15;
    const int wr = w >> 2, wc = w & 3;
    const int bx = (int)blockIdx.x;
    const int swz = (bx & 7) * ((int)gridDim.x >> 3) + (bx >> 3);
    const int r0 = swz * 64;
    const int gi = swz >> 6;            // 64 blocks per graph
    v4f acc[8][2];
    gemm_core<HID, HID>(hsrc + (size_t)r0 * HID, qwb, &sA[0][0], &sW[0][0], acc);

    float ss0 = 0.f, ss1 = 0.f, ws0 = 0.f, ws1 = 0.f;
    #pragma unroll
    for (int n = 0; n < 8; ++n) {
        int c = wc * 128 + n * 16 + q * 4;
        float4 kv = *(const float4*)(ks + (gi << 9) + c);
        const float* kp = &kv.x;
        #pragma unroll
        for (int rt = 0; rt < 2; ++rt)
            #pragma unroll
            for (int e = 0; e < 4; ++e) {
                float vv = acc[n][rt][e];
                if (vv == 0.f) vv = 1e-6f;
                acc[n][rt][e] = vv;
                if (rt == 0) { ss0 += vv * vv; ws0 += vv * kp[e]; }
                else         { ss1 += vv * vv; ws1 += vv * kp[e]; }
            }
    }
    ss0 += __shfl_xor(ss0, 16); ss0 += __shfl_xor(ss0, 32);
    ss1 += __shfl_xor(ss1, 16); ss1 += __shfl_xor(ss1, 32);
    ws0 += __shfl_xor(ws0, 16); ws0 += __shfl_xor(ws0, 32);
    ws1 += __shfl_xor(ws1, 16); ws1 += __shfl_xor(ws1, 32);
    if (lane < 16) {
        red[0][wr * 32 + m15][wc] = ss0; red[0][wr * 32 + 16 + m15][wc] = ss1;
        red[1][wr * 32 + m15][wc] = ws0; red[1][wr * 32 + 16 + m15][wc] = ws1;
    }
    __syncthreads();
    if (t < 64) {
        float st = red[0][t][0] + red[0][t][1] + red[0][t][2] + red[0][t][3];
        float wt = red[1][t][0] + red[1][t][1] + red[1][t][2] + red[1][t][3];
        float rn = rsqrtf(st);
        rowv[t] = rn;
        dnv[r0 + t] = 1.f / (rn * wt + (float)NNODE);
    }
    __syncthreads();
    #pragma unroll
    for (int n = 0; n < 8; ++n) {
        int c = wc * 128 + n * 16 + q * 4;
        #pragma unroll
        for (int rt = 0; rt < 2; ++rt) {
            int row = wr * 32 + rt * 16 + m15;
            float rn = rowv[row];
            *(uint2*)&qo[(size_t)(r0 + row) * HID + c] =
                pk4(acc[n][rt][0] * rn, acc[n][rt][1] * rn,
                    acc[n][rt][2] * rn, acc[n][rt][3] * rn);
        }
    }
}

// ---------------- num = qhat @ kvsT^T + residual + LN + ReLU ----------------
__launch_bounds__(512, 4)
__global__ void k_attn2(const u16* __restrict__ qhat, const u16* __restrict__ kvstb,
                        const float* __restrict__ dnv, const float* __restrict__ vsrc,
                        const u16* __restrict__ hsrc, const float* __restrict__ lg,
                        const float* __restrict__ lb, u16* __restrict__ outb,
                        float* __restrict__ outf) {
    __shared__ u16 sA[2][64 * 32];
    __shared__ u16 sW[2][512 * 32];
    __shared__ float red[2][64][4];
    __shared__ float rowv[2][64];
    const int t = threadIdx.x, lane = t & 63, w = t >> 6;
    const int q = lane >> 4, m15 = lane & 15;
    const int wr = w >> 2, wc = w & 3;
    const int bx = (int)blockIdx.x;
    const int swz = (bx & 7) * ((int)gridDim.x >> 3) + (bx >> 3);
    const int r0 = swz * 64;
    const int gi = swz >> 6;
    v4f acc[8][2];
    gemm_core<HID, HID>(qhat + (size_t)r0 * HID, kvstb + (size_t)gi * HID * HID,
                        &sA[0][0], &sW[0][0], acc);

    const float dv0 = dnv[r0 + wr * 32 + m15];
    const float dv1 = dnv[r0 + wr * 32 + 16 + m15];
    float sm0 = 0.f, sm1 = 0.f, sq0 = 0.f, sq1 = 0.f;
    #pragma unroll
    for (int n = 0; n < 8; ++n) {
        int c = wc * 128 + n * 16 + q * 4;
        #pragma unroll
        for (int rt = 0; rt < 2; ++rt) {
            int row = wr * 32 + rt * 16 + m15;
            size_t og = (size_t)(r0 + row) * HID + c;
            float hh[4]; up4(*(const uint2*)&hsrc[og], hh);
            float4 vv = *(const float4*)&vsrc[og];
            const float* vp = &vv.x;
            float dv = rt ? dv1 : dv0;
            #pragma unroll
            for (int e = 0; e < 4; ++e) {
                float a = ((acc[n][rt][e] + (float)NNODE * vp[e]) * dv + hh[e]) * 0.5f;
                acc[n][rt][e] = a;
                if (rt == 0) { sm0 += a; sq0 += a * a; } else { sm1 += a; sq1 += a * a; }
            }
        }
    }
    sm0 += __shfl_xor(sm0, 16); sm0 += __shfl_xor(sm0, 32);
    sq0 += __shfl_xor(sq0, 16); sq0 += __shfl_xor(sq0, 32);
    sm1 += __shfl_xor(sm1, 16); sm1 += __shfl_xor(sm1, 32);
    sq1 += __shfl_xor(sq1, 16); sq1 += __shfl_xor(sq1, 32);
    if (lane < 16) {
        red[0][wr * 32 + m15][wc] = sm0; red[0][wr * 32 + 16 + m15][wc] = sm1;
        red[1][wr * 32 + m15][wc] = sq0; red[1][wr * 32 + 16 + m15][wc] = sq1;
    }
    __syncthreads();
    if (t < 64) {
        float tt = red[0][t][0] + red[0][t][1] + red[0][t][2] + red[0][t][3];
        float t2 = red[1][t][0] + red[1][t][1] + red[1][t][2] + red[1][t][3];
        float mu = tt * (1.f / HID);
        float rs = rsqrtf(t2 * (1.f / HID) - mu * mu + 1e-5f);
        rowv[0][t] = mu; rowv[1][t] = rs;
    }
    __syncthreads();
    #pragma unroll
    for (int n = 0; n < 8; ++n) {
        int c = wc * 128 + n * 16 + q * 4;
        float4 g4 = *(const float4*)(lg + c);
        float4 b4 = *(const float4*)(lb + c);
        #pragma unroll
        for (int rt = 0; rt < 2; ++rt) {
            int row = wr * 32 + rt * 16 + m15;
            float mu = rowv[0][row], rs = rowv[1][row];
            float v0 = (acc[n][rt][0] - mu) * rs * g4.x + b4.x;
            float v1 = (acc[n][rt][1] - mu) * rs * g4.y + b4.y;
            float v2 = (acc[n][rt][2] - mu) * rs * g4.z + b4.z;
            float v3 = (acc[n][rt][3] - mu) * rs * g4.w + b4.w;
            v0 = v0 > 0.f ? v0 : 0.f; v1 = v1 > 0.f ? v1 : 0.f;
            v2 = v2 > 0.f ? v2 : 0.f; v3 = v3 > 0.f ? v3 : 0.f;
            size_t og = (size_t)(r0 + row) * HID + c;
            if (outf) {
                float4 o = {v0, v1, v2, v3};
                *(float4*)&outf[og] = o;
            } else {
                *(uint2*)&outb[og] = pk4(v0, v1, v2, v3);
            }
        }
    }
}

extern "C" void kernel_launch(void* const* d_in, const int* in_sizes, int n_in,
                              void* d_out, int out_size, void* d_ws, size_t ws_size,
                              hipStream_t stream) {
    const float* x    = (const float*)d_in[0];
    const float* fc0w = (const float*)d_in[1];
    const float* fc0b = (const float*)d_in[2];
    const float* ln0g = (const float*)d_in[3];
    const float* ln0b = (const float*)d_in[4];
    const float* q0w  = (const float*)d_in[5];
    const float* k0w  = (const float*)d_in[6];
    const float* v0w  = (const float*)d_in[7];
    const float* ln1g = (const float*)d_in[8];
    const float* ln1b = (const float*)d_in[9];
    const float* q1w  = (const float*)d_in[10];
    const float* k1w  = (const float*)d_in[11];
    const float* v1w  = (const float*)d_in[12];
    const float* ln2g = (const float*)d_in[13];
    const float* ln2b = (const float*)d_in[14];
    // batch (d_in[15]) = repeat(arange(16),4096): argsort == identity. unused.

    // workspace (~247 MB):
    //   H(64M) | Kt(64M) | Vt(64M, also Xb then qhat) | KVp bf16 x4(33.5M) |
    //   KVb bf16(8.4M) | KS(32K) | DNV(256K) | weights bf16(3.4M)
    const size_t M64 = (size_t)TNODES * HID * 2;          // 64 MiB
    const size_t PL  = (size_t)NGRAPH * HID * HID * 2;    // 8.39 MB plane
    char* wsc = (char*)d_ws;
    u16*   H   = (u16*)wsc;
    u16*   Kt  = (u16*)(wsc + M64);
    u16*   Vt  = (u16*)(wsc + 2 * M64);
    u16*   KVp = (u16*)(wsc + 3 * M64);
    u16*   KVb = (u16*)(wsc + 3 * M64 + 4 * PL);
    float* KS  = (float*)(wsc + 3 * M64 + 5 * PL);
    float* DNV = KS + NGRAPH * HID;
    u16*   Wc  = (u16*)((char*)DNV + (size_t)TNODES * sizeof(float));
    u16* fc0wb = Wc;
    u16* q0b = Wc + 131072;
    u16* k0b = Wc + 393216;
    u16* v0b = Wc + 655360;
    u16* q1b = Wc + 917504;
    u16* k1b = Wc + 1179648;
    u16* v1b = Wc + 1441792;
    u16* Xb  = Vt;                 // consumed by k_fc before layer-1 proj writes Vt
    u16* QH  = Vt;                 // qhat after kvmm consumed Vt
    float* V = (float*)d_out;      // fp32 v, in-place-safe vs final fp32 out

    dim3 b256(256), b512(512);
    k_cvt4<<<dim3(64),  b256, 0, stream>>>(fc0w, fc0wb, HID * INCH / 4);
    k_cvt4<<<dim3(64),  b256, 0, stream>>>(q0w, q0b, HID * HID / 4);
    k_cvt4<<<dim3(64),  b256, 0, stream>>>(k0w, k0b, HID * HID / 4);
    k_cvt4<<<dim3(64),  b256, 0, stream>>>(v0w, v0b, HID * HID / 4);
    k_cvt4<<<dim3(64),  b256, 0, stream>>>(q1w, q1b, HID * HID / 4);
    k_cvt4<<<dim3(64),  b256, 0, stream>>>(k1w, k1b, HID * HID / 4);
    k_cvt4<<<dim3(64),  b256, 0, stream>>>(v1w, v1b, HID * HID / 4);
    k_cvt4<<<dim3(1024), b256, 0, stream>>>(x, Xb, TNODES * INCH / 4);

    k_fc<<<dim3(TNODES / 64), b512, 0, stream>>>(Xb, fc0wb, fc0b, ln0g, ln0b, H);

    // ---- layer 1 ----
    k_zero<<<dim3(32), b256, 0, stream>>>(KS, NGRAPH * HID);
    k_proj<<<dim3(TNODES / 64, 2), b512, 0, stream>>>(H, k0b, v0b, Kt, Vt, V, KS);
    k_kvmm2<<<dim3(512), b512, 0, stream>>>(Kt, Vt, KVp);
    k_red4<<<dim3(2048), b256, 0, stream>>>(KVp, KVb, NGRAPH * HID * HID / 8);
    k_qnorm<<<dim3(TNODES / 64), b512, 0, stream>>>(H, q0b, KS, QH, DNV);
    k_attn2<<<dim3(TNODES / 64), b512, 0, stream>>>(QH, KVb, DNV, V, H, ln1g, ln1b,
                                                    H, nullptr);    // H := layer-1 out

    // ---- layer 2 ----
    k_zero<<<dim3(32), b256, 0, stream>>>(KS, NGRAPH * HID);
    k_proj<<<dim3(TNODES / 64, 2), b512, 0, stream>>>(H, k1b, v1b, Kt, Vt, V, KS);
    k_kvmm2<<<dim3(512), b512, 0, stream>>>(Kt, Vt, KVp);
    k_red4<<<dim3(2048), b256, 0, stream>>>(KVp, KVb, NGRAPH * HID * HID / 8);
    k_qnorm<<<dim3(TNODES / 64), b512, 0, stream>>>(H, q1b, KS, QH, DNV);
    k_attn2<<<dim3(TNODES / 64), b512, 0, stream>>>(QH, KVb, DNV, V, H, ln2g, ln2b,
                                                    nullptr, (float*)d_out);
}

// Round 5
// 1033.963 us; speedup vs baseline: 1.0588x; 1.0588x over previous
//
#include <hip/hip_runtime.h>

#define TNODES 65536
#define NGRAPH 16
#define NNODE  4096
#define INCH   256
#define HID    512

using u16 = unsigned short;
using u32 = unsigned int;
using v8s = __attribute__((ext_vector_type(8))) short;   // 8 bf16 (4 VGPRs)
using v4f = __attribute__((ext_vector_type(4))) float;   // 4 fp32 acc

__device__ __forceinline__ float bf2f(u16 u) {
    union { u32 i; float f; } v; v.i = ((u32)u) << 16; return v.f;
}
__device__ __forceinline__ u16 f2bf(float f) {
    union { float f; u32 i; } v; v.f = f;
    u32 x = v.i;
    return (u16)((x + 0x7fffu + ((x >> 16) & 1u)) >> 16);
}
__device__ __forceinline__ void up4(uint2 p, float* f) {
    f[0] = __uint_as_float(p.x << 16); f[1] = __uint_as_float(p.x & 0xffff0000u);
    f[2] = __uint_as_float(p.y << 16); f[3] = __uint_as_float(p.y & 0xffff0000u);
}
__device__ __forceinline__ uint2 pk4(float a, float b, float c, float d) {
    uint2 r;
    r.x = (u32)f2bf(a) | ((u32)f2bf(b) << 16);
    r.y = (u32)f2bf(c) | ((u32)f2bf(d) << 16);
    return r;
}

#define MFMA(a, b, c) __builtin_amdgcn_mfma_f32_16x16x32_bf16((a), (b), (c), 0, 0, 0)

// async global->LDS, 16B per lane. dest = wave-uniform base + lane*16 (linear).
#define GLD16(gp, sp) __builtin_amdgcn_global_load_lds( \
    (const __attribute__((address_space(1))) u32*)(const void*)(gp), \
    (__attribute__((address_space(3))) u32*)(void*)(sp), 16, 0, 0)

#define CFENCE() asm volatile("" ::: "memory")

// ---------------- fp32 -> bf16 convert, vectorized ----------------
__global__ void k_cvt4(const float* __restrict__ s, u16* __restrict__ d, int n4) {
    for (int i = blockIdx.x * blockDim.x + threadIdx.x; i < n4; i += gridDim.x * blockDim.x) {
        float4 f = ((const float4*)s)[i];
        ((uint2*)d)[i] = pk4(f.x, f.y, f.z, f.w);
    }
}

__global__ void k_zero(float* __restrict__ p, int n) {
    int i = blockIdx.x * 256 + threadIdx.x;
    if (i < n) p[i] = 0.f;
}

// ---------------- sum 4 bf16 partial planes -> bf16 ----------------
__global__ void k_red4(const u16* __restrict__ p, u16* __restrict__ o, int n8) {
    const size_t P = (size_t)NGRAPH * HID * HID;
    for (int i = blockIdx.x * blockDim.x + threadIdx.x; i < n8; i += gridDim.x * blockDim.x) {
        size_t b = (size_t)i * 8;
        float s[8] = {0.f, 0.f, 0.f, 0.f, 0.f, 0.f, 0.f, 0.f};
        #pragma unroll
        for (int ss = 0; ss < 4; ++ss) {
            v8s v = *(const v8s*)(p + ss * P + b);
            const u16* vp = (const u16*)&v;
            #pragma unroll
            for (int j = 0; j < 8; ++j) s[j] += bf2f(vp[j]);
        }
        uint2 lo = pk4(s[0], s[1], s[2], s[3]);
        uint2 hi = pk4(s[4], s[5], s[6], s[7]);
        uint4 w; w.x = lo.x; w.y = lo.y; w.z = hi.x; w.w = hi.y;
        *(uint4*)(o + b) = w;
    }
}

// =====================================================================
// GEMM core v2: C[128 x 512] = Act[128 rows, stride LDK] @ W[512 rows]^T.
// 512 threads = 8 waves (2 row-groups x 4 col-groups), wave tile 64x128
// (M_rep=4, N_rep=8, acc[8][4]) -> 42.7 FLOP per LDS byte (was 25.6 at
// 64-row blocks; the structure was LDS-BW-bound at MfmaUtil 19%).
// BK=32, double-buffered global_load_lds(16B), counted vmcnt(5).
// XOR-swizzle (slot ^= (row>>1)&3) on the GLOBAL source + same on ds_read.
// =====================================================================
template<int LDK, int KLEN>
__device__ __forceinline__ void gemm_core(const u16* __restrict__ A,
                                          const u16* __restrict__ W,
                                          u16* sA, u16* sW, v4f (&acc)[8][4]) {
    const int t = threadIdx.x, lane = t & 63;
    const int q = lane >> 4, m15 = lane & 15;
    const int w = t >> 6, wr = w >> 2, wc = w & 3;

    #pragma unroll
    for (int n = 0; n < 8; ++n)
        #pragma unroll
        for (int rt = 0; rt < 4; ++rt)
            #pragma unroll
            for (int e = 0; e < 4; ++e) acc[n][rt][e] = 0.f;

    int aoff[4], woff[8];
    #pragma unroll
    for (int rt = 0; rt < 4; ++rt) {
        int r = wr * 64 + rt * 16 + m15;
        aoff[rt] = r * 32 + ((q ^ ((r >> 1) & 3)) * 8);
    }
    #pragma unroll
    for (int n = 0; n < 8; ++n) {
        int r = wc * 128 + n * 16 + m15;
        woff[n] = r * 32 + ((q ^ ((r >> 1) & 3)) * 8);
    }

    auto stage = [&](int k0, int buf) {
        u16* dW = sW + buf * (512 * 32);
        #pragma unroll
        for (int p = 0; p < 4; ++p) {
            int sf = p * 512 + t, row = sf >> 2, sl = sf & 3;
            int gc = k0 + ((sl ^ ((row >> 1) & 3)) * 8);
            GLD16(W + (size_t)row * LDK + gc, dW + sf * 8);
        }
        {   // A-tile: 128 rows x 32, one 16B load per thread
            int row = t >> 2, sl = t & 3;
            int gc = k0 + ((sl ^ ((row >> 1) & 3)) * 8);
            GLD16(A + (size_t)row * LDK + gc, sA + buf * (128 * 32) + t * 8);
        }
    };

    const int KT = KLEN / 32;
    stage(0, 0);
    stage(32, 1);
    int cur = 0;
    for (int kt = 0; kt < KT; ++kt) {
        if (kt + 1 < KT) asm volatile("s_waitcnt vmcnt(5)" ::: "memory");
        else             asm volatile("s_waitcnt vmcnt(0)" ::: "memory");
        __builtin_amdgcn_s_barrier();
        CFENCE();
        __builtin_amdgcn_sched_barrier(0);
        const u16* cA = sA + cur * (128 * 32);
        const u16* cW = sW + cur * (512 * 32);
        v8s b[4];
        #pragma unroll
        for (int rt = 0; rt < 4; ++rt) b[rt] = *(const v8s*)(cA + aoff[rt]);
        #pragma unroll
        for (int n = 0; n < 8; ++n) {
            v8s af = *(const v8s*)(cW + woff[n]);
            #pragma unroll
            for (int rt = 0; rt < 4; ++rt)
                acc[n][rt] = MFMA(af, b[rt], acc[n][rt]);
        }
        CFENCE();
        __builtin_amdgcn_s_barrier();
        CFENCE();
        if (kt + 2 < KT) stage((kt + 2) * 32, cur);
        cur ^= 1;
    }
}

// acc element (n,rt,e) <-> A-row wr*64 + rt*16 + (lane&15),
//                          W-row wc*128 + n*16 + (lane>>4)*4 + e.

// transpose swizzle: X(c) = (((c>>2)&3)<<4) ^ ((c&3)<<3)
__device__ __forceinline__ int tswz(int c) {
    return (((c >> 2) & 3) << 4) ^ ((c & 3) << 3);
}

// ---------------- fc0 + LN + ReLU ----------------
__launch_bounds__(512, 2)
__global__ void k_fc(const u16* __restrict__ xb, const u16* __restrict__ wb,
                     const float* __restrict__ bias, const float* __restrict__ lg,
                     const float* __restrict__ lb, u16* __restrict__ h) {
    __shared__ u16 sA[2][128 * 32];
    __shared__ u16 sW[2][512 * 32];
    __shared__ float red[2][128][4];
    __shared__ float rowv[2][128];
    const int t = threadIdx.x, lane = t & 63, w = t >> 6;
    const int q = lane >> 4, m15 = lane & 15;
    const int wr = w >> 2, wc = w & 3;
    const int bx = (int)blockIdx.x;
    const int swz = (bx & 7) * ((int)gridDim.x >> 3) + (bx >> 3);
    const int r0 = swz * 128;
    v4f acc[8][4];
    gemm_core<INCH, INCH>(xb + (size_t)r0 * INCH, wb, &sA[0][0], &sW[0][0], acc);

    float sm[4] = {0.f, 0.f, 0.f, 0.f}, sq[4] = {0.f, 0.f, 0.f, 0.f};
    #pragma unroll
    for (int n = 0; n < 8; ++n) {
        int c = wc * 128 + n * 16 + q * 4;
        float4 bi = *(const float4*)(bias + c);
        const float* bp = &bi.x;
        #pragma unroll
        for (int rt = 0; rt < 4; ++rt)
            #pragma unroll
            for (int e = 0; e < 4; ++e) {
                float a = acc[n][rt][e] + bp[e];
                acc[n][rt][e] = a;
                sm[rt] += a; sq[rt] += a * a;
            }
    }
    #pragma unroll
    for (int rt = 0; rt < 4; ++rt) {
        sm[rt] += __shfl_xor(sm[rt], 16); sm[rt] += __shfl_xor(sm[rt], 32);
        sq[rt] += __shfl_xor(sq[rt], 16); sq[rt] += __shfl_xor(sq[rt], 32);
    }
    if (lane < 16)
        #pragma unroll
        for (int rt = 0; rt < 4; ++rt) {
            red[0][wr * 64 + rt * 16 + m15][wc] = sm[rt];
            red[1][wr * 64 + rt * 16 + m15][wc] = sq[rt];
        }
    __syncthreads();
    if (t < 128) {
        float tt = red[0][t][0] + red[0][t][1] + red[0][t][2] + red[0][t][3];
        float t2 = red[1][t][0] + red[1][t][1] + red[1][t][2] + red[1][t][3];
        float mu = tt * (1.f / HID);
        float rs = rsqrtf(t2 * (1.f / HID) - mu * mu + 1e-5f);
        rowv[0][t] = mu; rowv[1][t] = rs;
    }
    __syncthreads();
    #pragma unroll
    for (int n = 0; n < 8; ++n) {
        int c = wc * 128 + n * 16 + q * 4;
        float4 g4 = *(const float4*)(lg + c);
        float4 b4 = *(const float4*)(lb + c);
        #pragma unroll
        for (int rt = 0; rt < 4; ++rt) {
            int row = wr * 64 + rt * 16 + m15;
            float mu = rowv[0][row], rs = rowv[1][row];
            float v0 = (acc[n][rt][0] - mu) * rs * g4.x + b4.x;
            float v1 = (acc[n][rt][1] - mu) * rs * g4.y + b4.y;
            float v2 = (acc[n][rt][2] - mu) * rs * g4.z + b4.z;
            float v3 = (acc[n][rt][3] - mu) * rs * g4.w + b4.w;
            v0 = v0 > 0.f ? v0 : 0.f; v1 = v1 > 0.f ? v1 : 0.f;
            v2 = v2 > 0.f ? v2 : 0.f; v3 = v3 > 0.f ? v3 : 0.f;
            *(uint2*)&h[(size_t)(r0 + row) * HID + c] = pk4(v0, v1, v2, v3);
        }
    }
}

// ---------------- k/v projection + transposed outputs ----------------
// y==0: k -> eps + L2 row-normalize -> Kt[g][m][l] bf16, fused ks partials.
// y==1: v -> V fp32 identity + Vt[g][d][l] bf16.
// Transpose via the 64 KB sW region, two 64-row passes (pass == wr).
__launch_bounds__(512, 2)
__global__ void k_proj(const u16* __restrict__ hsrc, const u16* __restrict__ wkb,
                       const u16* __restrict__ wvb, u16* __restrict__ kt,
                       u16* __restrict__ vt, float* __restrict__ vo,
                       float* __restrict__ ksum) {
    __shared__ u16 sA[2][128 * 32];
    __shared__ u16 sW[2][512 * 32];
    __shared__ float red[128][4];
    __shared__ float rowv[128];
    u16* sT = &sW[0][0];                      // 512 ch x 64 rows (reuse)
    const int t = threadIdx.x, lane = t & 63, w = t >> 6;
    const int q = lane >> 4, m15 = lane & 15;
    const int wr = w >> 2, wc = w & 3;
    const int bx = (int)blockIdx.x;
    const int swz = (bx & 7) * ((int)gridDim.x >> 3) + (bx >> 3);
    const int r0 = swz * 128;
    const int g = swz >> 5;                   // 32 blocks per graph
    const int lbase = (swz & 31) * 128;
    const int mode = blockIdx.y;
    v4f acc[8][4];
    gemm_core<HID, HID>(hsrc + (size_t)r0 * HID, mode ? wvb : wkb,
                        &sA[0][0], &sW[0][0], acc);

    const int ch = t;
    const int xs = (((ch >> 2) & 3) << 1) ^ (ch & 3);   // tswz(ch)>>3
    if (mode == 0) {
        float sq[4] = {0.f, 0.f, 0.f, 0.f};
        #pragma unroll
        for (int n = 0; n < 8; ++n)
            #pragma unroll
            for (int rt = 0; rt < 4; ++rt)
                #pragma unroll
                for (int e = 0; e < 4; ++e) {
                    float vv = acc[n][rt][e];
                    if (vv == 0.f) vv = 1e-6f;
                    acc[n][rt][e] = vv;
                    sq[rt] += vv * vv;
                }
        #pragma unroll
        for (int rt = 0; rt < 4; ++rt) {
            sq[rt] += __shfl_xor(sq[rt], 16); sq[rt] += __shfl_xor(sq[rt], 32);
        }
        if (lane < 16)
            #pragma unroll
            for (int rt = 0; rt < 4; ++rt)
                red[wr * 64 + rt * 16 + m15][wc] = sq[rt];
        __syncthreads();
        if (t < 128)
            rowv[t] = rsqrtf(red[t][0] + red[t][1] + red[t][2] + red[t][3]);
        __syncthreads();
        float sum = 0.f;
        #pragma unroll
        for (int pass = 0; pass < 2; ++pass) {
            if (wr == pass) {
                #pragma unroll
                for (int n = 0; n < 8; ++n)
                    #pragma unroll
                    for (int rt = 0; rt < 4; ++rt) {
                        int rl = rt * 16 + m15;           // row within pass
                        float rn = rowv[wr * 64 + rl];
                        #pragma unroll
                        for (int e = 0; e < 4; ++e) {
                            int c = wc * 128 + n * 16 + q * 4 + e;
                            sT[(c << 6) + (rl ^ tswz(c))] = f2bf(acc[n][rt][e] * rn);
                        }
                    }
            }
            __syncthreads();
            u16* op = kt + ((size_t)(g * 512 + ch)) * NNODE + lbase + pass * 64;
            #pragma unroll
            for (int jj = 0; jj < 8; ++jj) {
                v8s cvec = *(const v8s*)&sT[(ch << 6) + jj * 8];
                int l0 = (jj ^ xs) * 8;
                *(v8s*)(op + l0) = cvec;
                const u16* cp = (const u16*)&cvec;
                #pragma unroll
                for (int i = 0; i < 8; ++i) sum += bf2f(cp[i]);
            }
            __syncthreads();
        }
        atomicAdd(&ksum[g * 512 + ch], sum);
    } else {
        #pragma unroll
        for (int n = 0; n < 8; ++n) {
            int c = wc * 128 + n * 16 + q * 4;
            #pragma unroll
            for (int rt = 0; rt < 4; ++rt) {
                int row = wr * 64 + rt * 16 + m15;
                float4 o = {acc[n][rt][0], acc[n][rt][1], acc[n][rt][2], acc[n][rt][3]};
                *(float4*)&vo[(size_t)(r0 + row) * HID + c] = o;
            }
        }
        #pragma unroll
        for (int pass = 0; pass < 2; ++pass) {
            if (wr == pass) {
                #pragma unroll
                for (int n = 0; n < 8; ++n)
                    #pragma unroll
                    for (int rt = 0; rt < 4; ++rt) {
                        int rl = rt * 16 + m15;
                        #pragma unroll
                        for (int e = 0; e < 4; ++e) {
                            int c = wc * 128 + n * 16 + q * 4 + e;
                            sT[(c << 6) + (rl ^ tswz(c))] = f2bf(acc[n][rt][e]);
                        }
                    }
            }
            __syncthreads();
            u16* op = vt + ((size_t)(g * 512 + ch)) * NNODE + lbase + pass * 64;
            #pragma unroll
            for (int jj = 0; jj < 8; ++jj) {
                v8s cvec = *(const v8s*)&sT[(ch << 6) + jj * 8];
                int l0 = (jj ^ xs) * 8;
                *(v8s*)(op + l0) = cvec;
            }
            __syncthreads();
        }
    }
}

// ---------------- kvsT partial[s][d][m] = sum_{l in split s} Vt[d][l]*Kt[m][l]
// grid: 256 blocks = 4 d-blocks x 4 l-splits x 16 graphs, chunked XCD swizzle
// (all db of one (g,s) Kt slice co-resident). Plain bf16 stores; k_red4 sums.
__launch_bounds__(512, 2)
__global__ void k_kvmm2(const u16* __restrict__ kt, const u16* __restrict__ vt,
                        u16* __restrict__ kvp) {
    __shared__ u16 sA[2][128 * 32];
    __shared__ u16 sW[2][512 * 32];
    const int t = threadIdx.x, lane = t & 63, w = t >> 6;
    const int q = lane >> 4, m15 = lane & 15;
    const int wr = w >> 2, wc = w & 3;
    const int bx = (int)blockIdx.x;
    const int swz = (bx & 7) * 32 + (bx >> 3);   // 256 blocks, 32/XCD chunk
    const int db = swz & 3, s = (swz >> 2) & 3, g = swz >> 4;
    const u16* A = vt + ((size_t)(g * 512 + db * 128)) * NNODE + s * 1024;
    const u16* W = kt + ((size_t)(g * 512)) * NNODE + s * 1024;
    v4f acc[8][4];
    gemm_core<NNODE, 1024>(A, W, &sA[0][0], &sW[0][0], acc);
    u16* plane = kvp + (size_t)s * NGRAPH * HID * HID;
    #pragma unroll
    for (int n = 0; n < 8; ++n) {
        int m = wc * 128 + n * 16 + q * 4;
        #pragma unroll
        for (int rt = 0; rt < 4; ++rt) {
            int d = db * 128 + wr * 64 + rt * 16 + m15;
            *(uint2*)&plane[((size_t)(g * 512) + d) * 512 + m] =
                pk4(acc[n][rt][0], acc[n][rt][1], acc[n][rt][2], acc[n][rt][3]);
        }
    }
}

// ---------------- q projection + normalize + denom ----------------
__launch_bounds__(512, 2)
__global__ void k_qnorm(const u16* __restrict__ hsrc, const u16* __restrict__ qwb,
                        const float* __restrict__ ks, u16* __restrict__ qo,
                        float* __restrict__ dnv) {
    __shared__ u16 sA[2][128 * 32];
    __shared__ u16 sW[2][512 * 32];
    __shared__ float red[2][128][4];
    __shared__ float rowv[128];
    const int t = threadIdx.x, lane = t & 63, w = t >> 6;
    const int q = lane >> 4, m15 = lane & 15;
    const int wr = w >> 2, wc = w & 3;
    const int bx = (int)blockIdx.x;
    const int swz = (bx & 7) * ((int)gridDim.x >> 3) + (bx >> 3);
    const int r0 = swz * 128;
    const int gi = swz >> 5;            // 32 blocks per graph
    v4f acc[8][4];
    gemm_core<HID, HID>(hsrc + (size_t)r0 * HID, qwb, &sA[0][0], &sW[0][0], acc);

    float ss[4] = {0.f, 0.f, 0.f, 0.f}, ws[4] = {0.f, 0.f, 0.f, 0.f};
    #pragma unroll
    for (int n = 0; n < 8; ++n) {
        int c = wc * 128 + n * 16 + q * 4;
        float4 kv = *(const float4*)(ks + (gi << 9) + c);
        const float* kp = &kv.x;
        #pragma unroll
        for (int rt = 0; rt < 4; ++rt)
            #pragma unroll
            for (int e = 0; e < 4; ++e) {
                float vv = acc[n][rt][e];
                if (vv == 0.f) vv = 1e-6f;
                acc[n][rt][e] = vv;
                ss[rt] += vv * vv; ws[rt] += vv * kp[e];
            }
    }
    #pragma unroll
    for (int rt = 0; rt < 4; ++rt) {
        ss[rt] += __shfl_xor(ss[rt], 16); ss[rt] += __shfl_xor(ss[rt], 32);
        ws[rt] += __shfl_xor(ws[rt], 16); ws[rt] += __shfl_xor(ws[rt], 32);
    }
    if (lane < 16)
        #pragma unroll
        for (int rt = 0; rt < 4; ++rt) {
            red[0][wr * 64 + rt * 16 + m15][wc] = ss[rt];
            red[1][wr * 64 + rt * 16 + m15][wc] = ws[rt];
        }
    __syncthreads();
    if (t < 128) {
        float st = red[0][t][0] + red[0][t][1] + red[0][t][2] + red[0][t][3];
        float wt = red[1][t][0] + red[1][t][1] + red[1][t][2] + red[1][t][3];
        float rn = rsqrtf(st);
        rowv[t] = rn;
        dnv[r0 + t] = 1.f / (rn * wt + (float)NNODE);
    }
    __syncthreads();
    #pragma unroll
    for (int n = 0; n < 8; ++n) {
        int c = wc * 128 + n * 16 + q * 4;
        #pragma unroll
        for (int rt = 0; rt < 4; ++rt) {
            int row = wr * 64 + rt * 16 + m15;
            float rn = rowv[row];
            *(uint2*)&qo[(size_t)(r0 + row) * HID + c] =
                pk4(acc[n][rt][0] * rn, acc[n][rt][1] * rn,
                    acc[n][rt][2] * rn, acc[n][rt][3] * rn);
        }
    }
}

// ---------------- num = qhat @ kvsT^T + residual + LN + ReLU ----------------
__launch_bounds__(512, 2)
__global__ void k_attn2(const u16* __restrict__ qhat, const u16* __restrict__ kvstb,
                        const float* __restrict__ dnv, const float* __restrict__ vsrc,
                        const u16* __restrict__ hsrc, const float* __restrict__ lg,
                        const float* __restrict__ lb, u16* __restrict__ outb,
                        float* __restrict__ outf) {
    __shared__ u16 sA[2][128 * 32];
    __shared__ u16 sW[2][512 * 32];
    __shared__ float red[2][128][4];
    __shared__ float rowv[2][128];
    const int t = threadIdx.x, lane = t & 63, w = t >> 6;
    const int q = lane >> 4, m15 = lane & 15;
    const int wr = w >> 2, wc = w & 3;
    const int bx = (int)blockIdx.x;
    const int swz = (bx & 7) * ((int)gridDim.x >> 3) + (bx >> 3);
    const int r0 = swz * 128;
    const int gi = swz >> 5;
    v4f acc[8][4];
    gemm_core<HID, HID>(qhat + (size_t)r0 * HID, kvstb + (size_t)gi * HID * HID,
                        &sA[0][0], &sW[0][0], acc);

    float dv[4];
    #pragma unroll
    for (int rt = 0; rt < 4; ++rt) dv[rt] = dnv[r0 + wr * 64 + rt * 16 + m15];
    float sm[4] = {0.f, 0.f, 0.f, 0.f}, sq[4] = {0.f, 0.f, 0.f, 0.f};
    #pragma unroll
    for (int n = 0; n < 8; ++n) {
        int c = wc * 128 + n * 16 + q * 4;
        #pragma unroll
        for (int rt = 0; rt < 4; ++rt) {
            int row = wr * 64 + rt * 16 + m15;
            size_t og = (size_t)(r0 + row) * HID + c;
            float hh[4]; up4(*(const uint2*)&hsrc[og], hh);
            float4 vv = *(const float4*)&vsrc[og];
            const float* vp = &vv.x;
            #pragma unroll
            for (int e = 0; e < 4; ++e) {
                float a = ((acc[n][rt][e] + (float)NNODE * vp[e]) * dv[rt] + hh[e]) * 0.5f;
                acc[n][rt][e] = a;
                sm[rt] += a; sq[rt] += a * a;
            }
        }
    }
    #pragma unroll
    for (int rt = 0; rt < 4; ++rt) {
        sm[rt] += __shfl_xor(sm[rt], 16); sm[rt] += __shfl_xor(sm[rt], 32);
        sq[rt] += __shfl_xor(sq[rt], 16); sq[rt] += __shfl_xor(sq[rt], 32);
    }
    if (lane < 16)
        #pragma unroll
        for (int rt = 0; rt < 4; ++rt) {
            red[0][wr * 64 + rt * 16 + m15][wc] = sm[rt];
            red[1][wr * 64 + rt * 16 + m15][wc] = sq[rt];
        }
    __syncthreads();
    if (t < 128) {
        float tt = red[0][t][0] + red[0][t][1] + red[0][t][2] + red[0][t][3];
        float t2 = red[1][t][0] + red[1][t][1] + red[1][t][2] + red[1][t][3];
        float mu = tt * (1.f / HID);
        float rs = rsqrtf(t2 * (1.f / HID) - mu * mu + 1e-5f);
        rowv[0][t] = mu; rowv[1][t] = rs;
    }
    __syncthreads();
    #pragma unroll
    for (int n = 0; n < 8; ++n) {
        int c = wc * 128 + n * 16 + q * 4;
        float4 g4 = *(const float4*)(lg + c);
        float4 b4 = *(const float4*)(lb + c);
        #pragma unroll
        for (int rt = 0; rt < 4; ++rt) {
            int row = wr * 64 + rt * 16 + m15;
            float mu = rowv[0][row], rs = rowv[1][row];
            float v0 = (acc[n][rt][0] - mu) * rs * g4.x + b4.x;
            float v1 = (acc[n][rt][1] - mu) * rs * g4.y + b4.y;
            float v2 = (acc[n][rt][2] - mu) * rs * g4.z + b4.z;
            float v3 = (acc[n][rt][3] - mu) * rs * g4.w + b4.w;
            v0 = v0 > 0.f ? v0 : 0.f; v1 = v1 > 0.f ? v1 : 0.f;
            v2 = v2 > 0.f ? v2 : 0.f; v3 = v3 > 0.f ? v3 : 0.f;
            size_t og = (size_t)(r0 + row) * HID + c;
            if (outf) {
                float4 o = {v0, v1, v2, v3};
                *(float4*)&outf[og] = o;
            } else {
                *(uint2*)&outb[og] = pk4(v0, v1, v2, v3);
            }
        }
    }
}

extern "C" void kernel_launch(void* const* d_in, const int* in_sizes, int n_in,
                              void* d_out, int out_size, void* d_ws, size_t ws_size,
                              hipStream_t stream) {
    const float* x    = (const float*)d_in[0];
    const float* fc0w = (const float*)d_in[1];
    const float* fc0b = (const float*)d_in[2];
    const float* ln0g = (const float*)d_in[3];
    const float* ln0b = (const float*)d_in[4];
    const float* q0w  = (const float*)d_in[5];
    const float* k0w  = (const float*)d_in[6];
    const float* v0w  = (const float*)d_in[7];
    const float* ln1g = (const float*)d_in[8];
    const float* ln1b = (const float*)d_in[9];
    const float* q1w  = (const float*)d_in[10];
    const float* k1w  = (const float*)d_in[11];
    const float* v1w  = (const float*)d_in[12];
    const float* ln2g = (const float*)d_in[13];
    const float* ln2b = (const float*)d_in[14];
    // batch (d_in[15]) = repeat(arange(16),4096): argsort == identity. unused.

    // workspace (~247 MB):
    //   H(64M) | Kt(64M) | Vt(64M, also Xb then qhat) | KVp bf16 x4(33.5M) |
    //   KVb bf16(8.4M) | KS(32K) | DNV(256K) | weights bf16(3.4M)
    const size_t M64 = (size_t)TNODES * HID * 2;          // 64 MiB
    const size_t PL  = (size_t)NGRAPH * HID * HID * 2;    // 8.39 MB plane
    char* wsc = (char*)d_ws;
    u16*   H   = (u16*)wsc;
    u16*   Kt  = (u16*)(wsc + M64);
    u16*   Vt  = (u16*)(wsc + 2 * M64);
    u16*   KVp = (u16*)(wsc + 3 * M64);
    u16*   KVb = (u16*)(wsc + 3 * M64 + 4 * PL);
    float* KS  = (float*)(wsc + 3 * M64 + 5 * PL);
    float* DNV = KS + NGRAPH * HID;
    u16*   Wc  = (u16*)((char*)DNV + (size_t)TNODES * sizeof(float));
    u16* fc0wb = Wc;
    u16* q0b = Wc + 131072;
    u16* k0b = Wc + 393216;
    u16* v0b = Wc + 655360;
    u16* q1b = Wc + 917504;
    u16* k1b = Wc + 1179648;
    u16* v1b = Wc + 1441792;
    u16* Xb  = Vt;                 // consumed by k_fc before layer-1 proj writes Vt
    u16* QH  = Vt;                 // qhat after kvmm consumed Vt
    float* V = (float*)d_out;      // fp32 v, in-place-safe vs final fp32 out

    dim3 b256(256), b512(512);
    k_cvt4<<<dim3(64),  b256, 0, stream>>>(fc0w, fc0wb, HID * INCH / 4);
    k_cvt4<<<dim3(64),  b256, 0, stream>>>(q0w, q0b, HID * HID / 4);
    k_cvt4<<<dim3(64),  b256, 0, stream>>>(k0w, k0b, HID * HID / 4);
    k_cvt4<<<dim3(64),  b256, 0, stream>>>(v0w, v0b, HID * HID / 4);
    k_cvt4<<<dim3(64),  b256, 0, stream>>>(q1w, q1b, HID * HID / 4);
    k_cvt4<<<dim3(64),  b256, 0, stream>>>(k1w, k1b, HID * HID / 4);
    k_cvt4<<<dim3(64),  b256, 0, stream>>>(v1w, v1b, HID * HID / 4);
    k_cvt4<<<dim3(1024), b256, 0, stream>>>(x, Xb, TNODES * INCH / 4);

    k_fc<<<dim3(TNODES / 128), b512, 0, stream>>>(Xb, fc0wb, fc0b, ln0g, ln0b, H);

    // ---- layer 1 ----
    k_zero<<<dim3(32), b256, 0, stream>>>(KS, NGRAPH * HID);
    k_proj<<<dim3(TNODES / 128, 2), b512, 0, stream>>>(H, k0b, v0b, Kt, Vt, V, KS);
    k_kvmm2<<<dim3(256), b512, 0, stream>>>(Kt, Vt, KVp);
    k_red4<<<dim3(2048), b256, 0, stream>>>(KVp, KVb, NGRAPH * HID * HID / 8);
    k_qnorm<<<dim3(TNODES / 128), b512, 0, stream>>>(H, q0b, KS, QH, DNV);
    k_attn2<<<dim3(TNODES / 128), b512, 0, stream>>>(QH, KVb, DNV, V, H, ln1g, ln1b,
                                                     H, nullptr);   // H := layer-1 out

    // ---- layer 2 ----
    k_zero<<<dim3(32), b256, 0, stream>>>(KS, NGRAPH * HID);
    k_proj<<<dim3(TNODES / 128, 2), b512, 0, stream>>>(H, k1b, v1b, Kt, Vt, V, KS);
    k_kvmm2<<<dim3(256), b512, 0, stream>>>(Kt, Vt, KVp);
    k_red4<<<dim3(2048), b256, 0, stream>>>(KVp, KVb, NGRAPH * HID * HID / 8);
    k_qnorm<<<dim3(TNODES / 128), b512, 0, stream>>>(H, q1b, KS, QH, DNV);
    k_attn2<<<dim3(TNODES / 128), b512, 0, stream>>>(QH, KVb, DNV, V, H, ln2g, ln2b,
                                                     nullptr, (float*)d_out);
}

// Round 6
// 909.666 us; speedup vs baseline: 1.2035x; 1.1366x over previous
//
#include <hip/hip_runtime.h>

#define TNODES 65536
#define NGRAPH 16
#define NNODE  4096
#define INCH   256
#define HID    512

using u16 = unsigned short;
using u32 = unsigned int;
using v8s = __attribute__((ext_vector_type(8))) short;   // 8 bf16 (4 VGPRs)
using v4f = __attribute__((ext_vector_type(4))) float;   // 4 fp32 acc

__device__ __forceinline__ float bf2f(u16 u) {
    union { u32 i; float f; } v; v.i = ((u32)u) << 16; return v.f;
}
__device__ __forceinline__ u16 f2bf(float f) {
    union { float f; u32 i; } v; v.f = f;
    u32 x = v.i;
    return (u16)((x + 0x7fffu + ((x >> 16) & 1u)) >> 16);
}
__device__ __forceinline__ void up4(uint2 p, float* f) {
    f[0] = __uint_as_float(p.x << 16); f[1] = __uint_as_float(p.x & 0xffff0000u);
    f[2] = __uint_as_float(p.y << 16); f[3] = __uint_as_float(p.y & 0xffff0000u);
}
__device__ __forceinline__ uint2 pk4(float a, float b, float c, float d) {
    uint2 r;
    r.x = (u32)f2bf(a) | ((u32)f2bf(b) << 16);
    r.y = (u32)f2bf(c) | ((u32)f2bf(d) << 16);
    return r;
}

#define MFMA(a, b, c) __builtin_amdgcn_mfma_f32_16x16x32_bf16((a), (b), (c), 0, 0, 0)

// async global->LDS, 16B per lane. dest = wave-uniform base + lane*16 (linear).
#define GLD16(gp, sp) __builtin_amdgcn_global_load_lds( \
    (const __attribute__((address_space(1))) u32*)(const void*)(gp), \
    (__attribute__((address_space(3))) u32*)(void*)(sp), 16, 0, 0)

#define CFENCE() asm volatile("" ::: "memory")

// ---------------- fp32 -> bf16 convert, vectorized ----------------
__global__ void k_cvt4(const float* __restrict__ s, u16* __restrict__ d, int n4) {
    for (int i = blockIdx.x * blockDim.x + threadIdx.x; i < n4; i += gridDim.x * blockDim.x) {
        float4 f = ((const float4*)s)[i];
        ((uint2*)d)[i] = pk4(f.x, f.y, f.z, f.w);
    }
}

__global__ void k_zero(float* __restrict__ p, int n) {
    int i = blockIdx.x * 256 + threadIdx.x;
    if (i < n) p[i] = 0.f;
}

// ---------------- sum 4 bf16 partial planes -> bf16 ----------------
__global__ void k_red4(const u16* __restrict__ p, u16* __restrict__ o, int n8) {
    const size_t P = (size_t)NGRAPH * HID * HID;
    for (int i = blockIdx.x * blockDim.x + threadIdx.x; i < n8; i += gridDim.x * blockDim.x) {
        size_t b = (size_t)i * 8;
        float s[8] = {0.f, 0.f, 0.f, 0.f, 0.f, 0.f, 0.f, 0.f};
        #pragma unroll
        for (int ss = 0; ss < 4; ++ss) {
            v8s v = *(const v8s*)(p + ss * P + b);
            const u16* vp = (const u16*)&v;
            #pragma unroll
            for (int j = 0; j < 8; ++j) s[j] += bf2f(vp[j]);
        }
        uint2 lo = pk4(s[0], s[1], s[2], s[3]);
        uint2 hi = pk4(s[4], s[5], s[6], s[7]);
        uint4 w; w.x = lo.x; w.y = lo.y; w.z = hi.x; w.w = hi.y;
        *(uint4*)(o + b) = w;
    }
}

// =====================================================================
// GEMM core v2: C[128 x 512] = Act[128 rows, stride LDK] @ W[512 rows]^T.
// 512 threads = 8 waves (2 row-groups x 4 col-groups), wave tile 64x128
// (acc[8][4], 42.7 FLOP/LDS-byte). BK=32, double-buffered
// global_load_lds(16B), counted vmcnt(5). XOR-swizzle on global source +
// same on ds_read. LDS = 16K (sA dbuf) + 64K (sW dbuf) = 80K exactly ->
// 2 blocks/CU (epilogue reductions alias the sA region, dead post-GEMM).
// =====================================================================
template<int LDK, int KLEN>
__device__ __forceinline__ void gemm_core(const u16* __restrict__ A,
                                          const u16* __restrict__ W,
                                          u16* sA, u16* sW, v4f (&acc)[8][4]) {
    const int t = threadIdx.x, lane = t & 63;
    const int q = lane >> 4, m15 = lane & 15;
    const int w = t >> 6, wr = w >> 2, wc = w & 3;

    #pragma unroll
    for (int n = 0; n < 8; ++n)
        #pragma unroll
        for (int rt = 0; rt < 4; ++rt)
            #pragma unroll
            for (int e = 0; e < 4; ++e) acc[n][rt][e] = 0.f;

    int aoff[4], woff[8];
    #pragma unroll
    for (int rt = 0; rt < 4; ++rt) {
        int r = wr * 64 + rt * 16 + m15;
        aoff[rt] = r * 32 + ((q ^ ((r >> 1) & 3)) * 8);
    }
    #pragma unroll
    for (int n = 0; n < 8; ++n) {
        int r = wc * 128 + n * 16 + m15;
        woff[n] = r * 32 + ((q ^ ((r >> 1) & 3)) * 8);
    }

    auto stage = [&](int k0, int buf) {
        u16* dW = sW + buf * (512 * 32);
        #pragma unroll
        for (int p = 0; p < 4; ++p) {
            int sf = p * 512 + t, row = sf >> 2, sl = sf & 3;
            int gc = k0 + ((sl ^ ((row >> 1) & 3)) * 8);
            GLD16(W + (size_t)row * LDK + gc, dW + sf * 8);
        }
        {   // A-tile: 128 rows x 32, one 16B load per thread
            int row = t >> 2, sl = t & 3;
            int gc = k0 + ((sl ^ ((row >> 1) & 3)) * 8);
            GLD16(A + (size_t)row * LDK + gc, sA + buf * (128 * 32) + t * 8);
        }
    };

    const int KT = KLEN / 32;
    stage(0, 0);
    stage(32, 1);
    int cur = 0;
    for (int kt = 0; kt < KT; ++kt) {
        if (kt + 1 < KT) asm volatile("s_waitcnt vmcnt(5)" ::: "memory");
        else             asm volatile("s_waitcnt vmcnt(0)" ::: "memory");
        __builtin_amdgcn_s_barrier();
        CFENCE();
        __builtin_amdgcn_sched_barrier(0);
        const u16* cA = sA + cur * (128 * 32);
        const u16* cW = sW + cur * (512 * 32);
        v8s b[4];
        #pragma unroll
        for (int rt = 0; rt < 4; ++rt) b[rt] = *(const v8s*)(cA + aoff[rt]);
        #pragma unroll
        for (int n = 0; n < 8; ++n) {
            v8s af = *(const v8s*)(cW + woff[n]);
            #pragma unroll
            for (int rt = 0; rt < 4; ++rt)
                acc[n][rt] = MFMA(af, b[rt], acc[n][rt]);
        }
        CFENCE();
        __builtin_amdgcn_s_barrier();
        CFENCE();
        if (kt + 2 < KT) stage((kt + 2) * 32, cur);
        cur ^= 1;
    }
}

// acc element (n,rt,e) <-> A-row wr*64 + rt*16 + (lane&15),
//                          W-row wc*128 + n*16 + (lane>>4)*4 + e.

// transpose swizzle: X(c) = (((c>>2)&3)<<4) ^ ((c&3)<<3)
__device__ __forceinline__ int tswz(int c) {
    return (((c >> 2) & 3) << 4) ^ ((c & 3) << 3);
}

#define SMEM_DECL __shared__ char smem[81920]
#define SA ((u16*)smem)
#define SW ((u16*)(smem + 16384))

// ---------------- fc0 + LN + ReLU ----------------
__launch_bounds__(512, 2)
__global__ void k_fc(const u16* __restrict__ xb, const u16* __restrict__ wb,
                     const float* __restrict__ bias, const float* __restrict__ lg,
                     const float* __restrict__ lb, u16* __restrict__ h) {
    SMEM_DECL;
    float (*redA)[4] = (float(*)[4])smem;              // [128][4]
    float (*redB)[4] = (float(*)[4])(smem + 2048);     // [128][4]
    float* mu_s = (float*)(smem + 4096);               // [128]
    float* rs_s = (float*)(smem + 4608);               // [128]
    const int t = threadIdx.x, lane = t & 63, w = t >> 6;
    const int q = lane >> 4, m15 = lane & 15;
    const int wr = w >> 2, wc = w & 3;
    const int bx = (int)blockIdx.x;
    const int swz = (bx & 7) * ((int)gridDim.x >> 3) + (bx >> 3);
    const int r0 = swz * 128;
    v4f acc[8][4];
    gemm_core<INCH, INCH>(xb + (size_t)r0 * INCH, wb, SA, SW, acc);

    float sm[4] = {0.f, 0.f, 0.f, 0.f}, sq[4] = {0.f, 0.f, 0.f, 0.f};
    #pragma unroll
    for (int n = 0; n < 8; ++n) {
        int c = wc * 128 + n * 16 + q * 4;
        float4 bi = *(const float4*)(bias + c);
        const float* bp = &bi.x;
        #pragma unroll
        for (int rt = 0; rt < 4; ++rt)
            #pragma unroll
            for (int e = 0; e < 4; ++e) {
                float a = acc[n][rt][e] + bp[e];
                acc[n][rt][e] = a;
                sm[rt] += a; sq[rt] += a * a;
            }
    }
    #pragma unroll
    for (int rt = 0; rt < 4; ++rt) {
        sm[rt] += __shfl_xor(sm[rt], 16); sm[rt] += __shfl_xor(sm[rt], 32);
        sq[rt] += __shfl_xor(sq[rt], 16); sq[rt] += __shfl_xor(sq[rt], 32);
    }
    if (lane < 16)
        #pragma unroll
        for (int rt = 0; rt < 4; ++rt) {
            redA[wr * 64 + rt * 16 + m15][wc] = sm[rt];
            redB[wr * 64 + rt * 16 + m15][wc] = sq[rt];
        }
    __syncthreads();
    if (t < 128) {
        float tt = redA[t][0] + redA[t][1] + redA[t][2] + redA[t][3];
        float t2 = redB[t][0] + redB[t][1] + redB[t][2] + redB[t][3];
        float mu = tt * (1.f / HID);
        float rs = rsqrtf(t2 * (1.f / HID) - mu * mu + 1e-5f);
        mu_s[t] = mu; rs_s[t] = rs;
    }
    __syncthreads();
    #pragma unroll
    for (int n = 0; n < 8; ++n) {
        int c = wc * 128 + n * 16 + q * 4;
        float4 g4 = *(const float4*)(lg + c);
        float4 b4 = *(const float4*)(lb + c);
        #pragma unroll
        for (int rt = 0; rt < 4; ++rt) {
            int row = wr * 64 + rt * 16 + m15;
            float mu = mu_s[row], rs = rs_s[row];
            float v0 = (acc[n][rt][0] - mu) * rs * g4.x + b4.x;
            float v1 = (acc[n][rt][1] - mu) * rs * g4.y + b4.y;
            float v2 = (acc[n][rt][2] - mu) * rs * g4.z + b4.z;
            float v3 = (acc[n][rt][3] - mu) * rs * g4.w + b4.w;
            v0 = v0 > 0.f ? v0 : 0.f; v1 = v1 > 0.f ? v1 : 0.f;
            v2 = v2 > 0.f ? v2 : 0.f; v3 = v3 > 0.f ? v3 : 0.f;
            *(uint2*)&h[(size_t)(r0 + row) * HID + c] = pk4(v0, v1, v2, v3);
        }
    }
}

// ---------------- k/v projection + transposed outputs ----------------
// y==0: k -> eps + L2 row-normalize -> Kt[g][m][l] bf16, fused ks partials.
// y==1: v -> Vt[g][d][l] bf16 ONLY (no fp32 identity copy; attn2 reads Vt).
// Transpose via the 64 KB sW region, two 64-row passes (pass == wr).
__launch_bounds__(512, 2)
__global__ void k_proj(const u16* __restrict__ hsrc, const u16* __restrict__ wkb,
                       const u16* __restrict__ wvb, u16* __restrict__ kt,
                       u16* __restrict__ vt, float* __restrict__ ksum) {
    SMEM_DECL;
    float (*red)[4] = (float(*)[4])smem;               // [128][4]
    float* rowv = (float*)(smem + 2048);               // [128]
    u16* sT = SW;                                      // 512 ch x 64 rows
    const int t = threadIdx.x, lane = t & 63, w = t >> 6;
    const int q = lane >> 4, m15 = lane & 15;
    const int wr = w >> 2, wc = w & 3;
    const int bx = (int)blockIdx.x;
    const int swz = (bx & 7) * ((int)gridDim.x >> 3) + (bx >> 3);
    const int r0 = swz * 128;
    const int g = swz >> 5;                   // 32 blocks per graph
    const int lbase = (swz & 31) * 128;
    const int mode = blockIdx.y;
    v4f acc[8][4];
    gemm_core<HID, HID>(hsrc + (size_t)r0 * HID, mode ? wvb : wkb, SA, SW, acc);

    const int ch = t;
    const int xs = (((ch >> 2) & 3) << 1) ^ (ch & 3);   // tswz(ch)>>3
    if (mode == 0) {
        float sq[4] = {0.f, 0.f, 0.f, 0.f};
        #pragma unroll
        for (int n = 0; n < 8; ++n)
            #pragma unroll
            for (int rt = 0; rt < 4; ++rt)
                #pragma unroll
                for (int e = 0; e < 4; ++e) {
                    float vv = acc[n][rt][e];
                    if (vv == 0.f) vv = 1e-6f;
                    acc[n][rt][e] = vv;
                    sq[rt] += vv * vv;
                }
        #pragma unroll
        for (int rt = 0; rt < 4; ++rt) {
            sq[rt] += __shfl_xor(sq[rt], 16); sq[rt] += __shfl_xor(sq[rt], 32);
        }
        if (lane < 16)
            #pragma unroll
            for (int rt = 0; rt < 4; ++rt)
                red[wr * 64 + rt * 16 + m15][wc] = sq[rt];
        __syncthreads();
        if (t < 128)
            rowv[t] = rsqrtf(red[t][0] + red[t][1] + red[t][2] + red[t][3]);
        __syncthreads();
        float sum = 0.f;
        #pragma unroll
        for (int pass = 0; pass < 2; ++pass) {
            if (wr == pass) {
                #pragma unroll
                for (int n = 0; n < 8; ++n)
                    #pragma unroll
                    for (int rt = 0; rt < 4; ++rt) {
                        int rl = rt * 16 + m15;           // row within pass
                        float rn = rowv[wr * 64 + rl];
                        #pragma unroll
                        for (int e = 0; e < 4; ++e) {
                            int c = wc * 128 + n * 16 + q * 4 + e;
                            sT[(c << 6) + (rl ^ tswz(c))] = f2bf(acc[n][rt][e] * rn);
                        }
                    }
            }
            __syncthreads();
            u16* op = kt + ((size_t)(g * 512 + ch)) * NNODE + lbase + pass * 64;
            #pragma unroll
            for (int jj = 0; jj < 8; ++jj) {
                v8s cvec = *(const v8s*)&sT[(ch << 6) + jj * 8];
                int l0 = (jj ^ xs) * 8;
                *(v8s*)(op + l0) = cvec;
                const u16* cp = (const u16*)&cvec;
                #pragma unroll
                for (int i = 0; i < 8; ++i) sum += bf2f(cp[i]);
            }
            __syncthreads();
        }
        atomicAdd(&ksum[g * 512 + ch], sum);
    } else {
        #pragma unroll
        for (int pass = 0; pass < 2; ++pass) {
            if (wr == pass) {
                #pragma unroll
                for (int n = 0; n < 8; ++n)
                    #pragma unroll
                    for (int rt = 0; rt < 4; ++rt) {
                        int rl = rt * 16 + m15;
                        #pragma unroll
                        for (int e = 0; e < 4; ++e) {
                            int c = wc * 128 + n * 16 + q * 4 + e;
                            sT[(c << 6) + (rl ^ tswz(c))] = f2bf(acc[n][rt][e]);
                        }
                    }
            }
            __syncthreads();
            u16* op = vt + ((size_t)(g * 512 + ch)) * NNODE + lbase + pass * 64;
            #pragma unroll
            for (int jj = 0; jj < 8; ++jj) {
                v8s cvec = *(const v8s*)&sT[(ch << 6) + jj * 8];
                int l0 = (jj ^ xs) * 8;
                *(v8s*)(op + l0) = cvec;
            }
            __syncthreads();
        }
    }
}

// ---------------- kvsT partial[s][d][m] = sum_{l in split s} Vt[d][l]*Kt[m][l]
// grid: 256 blocks = 4 d-blocks x 4 l-splits x 16 graphs, chunked XCD swizzle.
__launch_bounds__(512, 2)
__global__ void k_kvmm2(const u16* __restrict__ kt, const u16* __restrict__ vt,
                        u16* __restrict__ kvp) {
    SMEM_DECL;
    const int t = threadIdx.x, lane = t & 63, w = t >> 6;
    const int q = lane >> 4, m15 = lane & 15;
    const int wr = w >> 2, wc = w & 3;
    const int bx = (int)blockIdx.x;
    const int swz = (bx & 7) * 32 + (bx >> 3);   // 256 blocks, 32/XCD chunk
    const int db = swz & 3, s = (swz >> 2) & 3, g = swz >> 4;
    const u16* A = vt + ((size_t)(g * 512 + db * 128)) * NNODE + s * 1024;
    const u16* W = kt + ((size_t)(g * 512)) * NNODE + s * 1024;
    v4f acc[8][4];
    gemm_core<NNODE, 1024>(A, W, SA, SW, acc);
    u16* plane = kvp + (size_t)s * NGRAPH * HID * HID;
    #pragma unroll
    for (int n = 0; n < 8; ++n) {
        int m = wc * 128 + n * 16 + q * 4;
        #pragma unroll
        for (int rt = 0; rt < 4; ++rt) {
            int d = db * 128 + wr * 64 + rt * 16 + m15;
            *(uint2*)&plane[((size_t)(g * 512) + d) * 512 + m] =
                pk4(acc[n][rt][0], acc[n][rt][1], acc[n][rt][2], acc[n][rt][3]);
        }
    }
}

// ---------------- q projection + normalize + denom ----------------
__launch_bounds__(512, 2)
__global__ void k_qnorm(const u16* __restrict__ hsrc, const u16* __restrict__ qwb,
                        const float* __restrict__ ks, u16* __restrict__ qo,
                        float* __restrict__ dnv) {
    SMEM_DECL;
    float (*redA)[4] = (float(*)[4])smem;              // ss
    float (*redB)[4] = (float(*)[4])(smem + 2048);     // ws
    float* rowv = (float*)(smem + 4096);               // rn
    const int t = threadIdx.x, lane = t & 63, w = t >> 6;
    const int q = lane >> 4, m15 = lane & 15;
    const int wr = w >> 2, wc = w & 3;
    const int bx = (int)blockIdx.x;
    const int swz = (bx & 7) * ((int)gridDim.x >> 3) + (bx >> 3);
    const int r0 = swz * 128;
    const int gi = swz >> 5;            // 32 blocks per graph
    v4f acc[8][4];
    gemm_core<HID, HID>(hsrc + (size_t)r0 * HID, qwb, SA, SW, acc);

    float ss[4] = {0.f, 0.f, 0.f, 0.f}, ws[4] = {0.f, 0.f, 0.f, 0.f};
    #pragma unroll
    for (int n = 0; n < 8; ++n) {
        int c = wc * 128 + n * 16 + q * 4;
        float4 kv = *(const float4*)(ks + (gi << 9) + c);
        const float* kp = &kv.x;
        #pragma unroll
        for (int rt = 0; rt < 4; ++rt)
            #pragma unroll
            for (int e = 0; e < 4; ++e) {
                float vv = acc[n][rt][e];
                if (vv == 0.f) vv = 1e-6f;
                acc[n][rt][e] = vv;
                ss[rt] += vv * vv; ws[rt] += vv * kp[e];
            }
    }
    #pragma unroll
    for (int rt = 0; rt < 4; ++rt) {
        ss[rt] += __shfl_xor(ss[rt], 16); ss[rt] += __shfl_xor(ss[rt], 32);
        ws[rt] += __shfl_xor(ws[rt], 16); ws[rt] += __shfl_xor(ws[rt], 32);
    }
    if (lane < 16)
        #pragma unroll
        for (int rt = 0; rt < 4; ++rt) {
            redA[wr * 64 + rt * 16 + m15][wc] = ss[rt];
            redB[wr * 64 + rt * 16 + m15][wc] = ws[rt];
        }
    __syncthreads();
    if (t < 128) {
        float st = redA[t][0] + redA[t][1] + redA[t][2] + redA[t][3];
        float wt = redB[t][0] + redB[t][1] + redB[t][2] + redB[t][3];
        float rn = rsqrtf(st);
        rowv[t] = rn;
        dnv[r0 + t] = 1.f / (rn * wt + (float)NNODE);
    }
    __syncthreads();
    #pragma unroll
    for (int n = 0; n < 8; ++n) {
        int c = wc * 128 + n * 16 + q * 4;
        #pragma unroll
        for (int rt = 0; rt < 4; ++rt) {
            int row = wr * 64 + rt * 16 + m15;
            float rn = rowv[row];
            *(uint2*)&qo[(size_t)(r0 + row) * HID + c] =
                pk4(acc[n][rt][0] * rn, acc[n][rt][1] * rn,
                    acc[n][rt][2] * rn, acc[n][rt][3] * rn);
        }
    }
}

// ---------------- num = qhat @ kvsT^T + residual + LN + ReLU ----------------
// v comes from the transposed bf16 Vt (scalar u16 loads, 16-lane-contiguous
// 32B segments; replaces the 128MB fp32 V write + read per layer).
__launch_bounds__(512, 2)
__global__ void k_attn2(const u16* __restrict__ qhat, const u16* __restrict__ kvstb,
                        const float* __restrict__ dnv, const u16* __restrict__ vt,
                        const u16* __restrict__ hsrc, const float* __restrict__ lg,
                        const float* __restrict__ lb, u16* __restrict__ outb,
                        float* __restrict__ outf) {
    SMEM_DECL;
    float (*redA)[4] = (float(*)[4])smem;
    float (*redB)[4] = (float(*)[4])(smem + 2048);
    float* mu_s = (float*)(smem + 4096);
    float* rs_s = (float*)(smem + 4608);
    const int t = threadIdx.x, lane = t & 63, w = t >> 6;
    const int q = lane >> 4, m15 = lane & 15;
    const int wr = w >> 2, wc = w & 3;
    const int bx = (int)blockIdx.x;
    const int swz = (bx & 7) * ((int)gridDim.x >> 3) + (bx >> 3);
    const int r0 = swz * 128;
    const int gi = swz >> 5;
    v4f acc[8][4];
    gemm_core<HID, HID>(qhat + (size_t)r0 * HID, kvstb + (size_t)gi * HID * HID,
                        SA, SW, acc);

    float dv[4];
    #pragma unroll
    for (int rt = 0; rt < 4; ++rt) dv[rt] = dnv[r0 + wr * 64 + rt * 16 + m15];
    // Vt base for this thread's rows: within-graph row = (swz&31)*128 + wr*64 + m15
    const u16* vtg = vt + (size_t)(gi * 512) * NNODE + ((swz & 31) * 128 + wr * 64 + m15);
    float sm[4] = {0.f, 0.f, 0.f, 0.f}, sq[4] = {0.f, 0.f, 0.f, 0.f};
    #pragma unroll
    for (int n = 0; n < 8; ++n) {
        int c = wc * 128 + n * 16 + q * 4;
        const u16* vb = vtg + (size_t)c * NNODE;
        #pragma unroll
        for (int rt = 0; rt < 4; ++rt) {
            int row = wr * 64 + rt * 16 + m15;
            size_t og = (size_t)(r0 + row) * HID + c;
            float hh[4]; up4(*(const uint2*)&hsrc[og], hh);
            #pragma unroll
            for (int e = 0; e < 4; ++e) {
                float vv = bf2f(vb[(size_t)e * NNODE + rt * 16]);
                float a = ((acc[n][rt][e] + (float)NNODE * vv) * dv[rt] + hh[e]) * 0.5f;
                acc[n][rt][e] = a;
                sm[rt] += a; sq[rt] += a * a;
            }
        }
    }
    #pragma unroll
    for (int rt = 0; rt < 4; ++rt) {
        sm[rt] += __shfl_xor(sm[rt], 16); sm[rt] += __shfl_xor(sm[rt], 32);
        sq[rt] += __shfl_xor(sq[rt], 16); sq[rt] += __shfl_xor(sq[rt], 32);
    }
    if (lane < 16)
        #pragma unroll
        for (int rt = 0; rt < 4; ++rt) {
            redA[wr * 64 + rt * 16 + m15][wc] = sm[rt];
            redB[wr * 64 + rt * 16 + m15][wc] = sq[rt];
        }
    __syncthreads();
    if (t < 128) {
        float tt = redA[t][0] + redA[t][1] + redA[t][2] + redA[t][3];
        float t2 = redB[t][0] + redB[t][1] + redB[t][2] + redB[t][3];
        float mu = tt * (1.f / HID);
        float rs = rsqrtf(t2 * (1.f / HID) - mu * mu + 1e-5f);
        mu_s[t] = mu; rs_s[t] = rs;
    }
    __syncthreads();
    #pragma unroll
    for (int n = 0; n < 8; ++n) {
        int c = wc * 128 + n * 16 + q * 4;
        float4 g4 = *(const float4*)(lg + c);
        float4 b4 = *(const float4*)(lb + c);
        #pragma unroll
        for (int rt = 0; rt < 4; ++rt) {
            int row = wr * 64 + rt * 16 + m15;
            float mu = mu_s[row], rs = rs_s[row];
            float v0 = (acc[n][rt][0] - mu) * rs * g4.x + b4.x;
            float v1 = (acc[n][rt][1] - mu) * rs * g4.y + b4.y;
            float v2 = (acc[n][rt][2] - mu) * rs * g4.z + b4.z;
            float v3 = (acc[n][rt][3] - mu) * rs * g4.w + b4.w;
            v0 = v0 > 0.f ? v0 : 0.f; v1 = v1 > 0.f ? v1 : 0.f;
            v2 = v2 > 0.f ? v2 : 0.f; v3 = v3 > 0.f ? v3 : 0.f;
            size_t og = (size_t)(r0 + row) * HID + c;
            if (outf) {
                float4 o = {v0, v1, v2, v3};
                *(float4*)&outf[og] = o;
            } else {
                *(uint2*)&outb[og] = pk4(v0, v1, v2, v3);
            }
        }
    }
}

extern "C" void kernel_launch(void* const* d_in, const int* in_sizes, int n_in,
                              void* d_out, int out_size, void* d_ws, size_t ws_size,
                              hipStream_t stream) {
    const float* x    = (const float*)d_in[0];
    const float* fc0w = (const float*)d_in[1];
    const float* fc0b = (const float*)d_in[2];
    const float* ln0g = (const float*)d_in[3];
    const float* ln0b = (const float*)d_in[4];
    const float* q0w  = (const float*)d_in[5];
    const float* k0w  = (const float*)d_in[6];
    const float* v0w  = (const float*)d_in[7];
    const float* ln1g = (const float*)d_in[8];
    const float* ln1b = (const float*)d_in[9];
    const float* q1w  = (const float*)d_in[10];
    const float* k1w  = (const float*)d_in[11];
    const float* v1w  = (const float*)d_in[12];
    const float* ln2g = (const float*)d_in[13];
    const float* ln2b = (const float*)d_in[14];
    // batch (d_in[15]) = repeat(arange(16),4096): argsort == identity. unused.

    // workspace (~247 MB):
    //   H(64M) | Kt(64M) | Vt(64M, also Xb then qhat... NOTE: Vt stays live
    //   through attn2 now, qhat gets its own KVp-adjacent slot? No -- qhat
    //   still aliases nothing: QH uses the Kt region after kvmm2 consumed Kt.
    const size_t M64 = (size_t)TNODES * HID * 2;          // 64 MiB
    const size_t PL  = (size_t)NGRAPH * HID * HID * 2;    // 8.39 MB plane
    char* wsc = (char*)d_ws;
    u16*   H   = (u16*)wsc;
    u16*   Kt  = (u16*)(wsc + M64);
    u16*   Vt  = (u16*)(wsc + 2 * M64);
    u16*   KVp = (u16*)(wsc + 3 * M64);
    u16*   KVb = (u16*)(wsc + 3 * M64 + 4 * PL);
    float* KS  = (float*)(wsc + 3 * M64 + 5 * PL);
    float* DNV = KS + NGRAPH * HID;
    u16*   Wc  = (u16*)((char*)DNV + (size_t)TNODES * sizeof(float));
    u16* fc0wb = Wc;
    u16* q0b = Wc + 131072;
    u16* k0b = Wc + 393216;
    u16* v0b = Wc + 655360;
    u16* q1b = Wc + 917504;
    u16* k1b = Wc + 1179648;
    u16* v1b = Wc + 1441792;
    u16* Xb  = Vt;                 // consumed by k_fc before layer-1 proj writes Vt
    u16* QH  = Kt;                 // qhat overwrites Kt after kvmm2 consumed it
                                   // (Vt must stay live for attn2's v reads)

    dim3 b256(256), b512(512);
    k_cvt4<<<dim3(64),  b256, 0, stream>>>(fc0w, fc0wb, HID * INCH / 4);
    k_cvt4<<<dim3(64),  b256, 0, stream>>>(q0w, q0b, HID * HID / 4);
    k_cvt4<<<dim3(64),  b256, 0, stream>>>(k0w, k0b, HID * HID / 4);
    k_cvt4<<<dim3(64),  b256, 0, stream>>>(v0w, v0b, HID * HID / 4);
    k_cvt4<<<dim3(64),  b256, 0, stream>>>(q1w, q1b, HID * HID / 4);
    k_cvt4<<<dim3(64),  b256, 0, stream>>>(k1w, k1b, HID * HID / 4);
    k_cvt4<<<dim3(64),  b256, 0, stream>>>(v1w, v1b, HID * HID / 4);
    k_cvt4<<<dim3(1024), b256, 0, stream>>>(x, Xb, TNODES * INCH / 4);

    k_fc<<<dim3(TNODES / 128), b512, 0, stream>>>(Xb, fc0wb, fc0b, ln0g, ln0b, H);

    // ---- layer 1 ----
    k_zero<<<dim3(32), b256, 0, stream>>>(KS, NGRAPH * HID);
    k_proj<<<dim3(TNODES / 128, 2), b512, 0, stream>>>(H, k0b, v0b, Kt, Vt, KS);
    k_kvmm2<<<dim3(256), b512, 0, stream>>>(Kt, Vt, KVp);
    k_red4<<<dim3(2048), b256, 0, stream>>>(KVp, KVb, NGRAPH * HID * HID / 8);
    k_qnorm<<<dim3(TNODES / 128), b512, 0, stream>>>(H, q0b, KS, QH, DNV);
    k_attn2<<<dim3(TNODES / 128), b512, 0, stream>>>(QH, KVb, DNV, Vt, H, ln1g, ln1b,
                                                     H, nullptr);   // H := layer-1 out

    // ---- layer 2 ----
    k_zero<<<dim3(32), b256, 0, stream>>>(KS, NGRAPH * HID);
    k_proj<<<dim3(TNODES / 128, 2), b512, 0, stream>>>(H, k1b, v1b, Kt, Vt, KS);
    k_kvmm2<<<dim3(256), b512, 0, stream>>>(Kt, Vt, KVp);
    k_red4<<<dim3(2048), b256, 0, stream>>>(KVp, KVb, NGRAPH * HID * HID / 8);
    k_qnorm<<<dim3(TNODES / 128), b512, 0, stream>>>(H, q1b, KS, QH, DNV);
    k_attn2<<<dim3(TNODES / 128), b512, 0, stream>>>(QH, KVb, DNV, Vt, H, ln2g, ln2b,
                                                     nullptr, (float*)d_out);
}